// Round 6
// baseline (2472.507 us; speedup 1.0000x reference)
//
#include <hip/hip_runtime.h>
#include <stdint.h>
#include <stdio.h>

typedef unsigned short ushort_t;
typedef float   f32x4  __attribute__((ext_vector_type(4)));
typedef short   bf16x8 __attribute__((ext_vector_type(8)));

#define B_    256
#define T_    256
#define IN_   256
#define HID_  512

// ---------------- workspace layout (bytes) ----------------
// ctr word indices:
//   [   0..1023] pure (L2-atomic) barrier counters: (g*2+round)*32
//   [1024..2047] fallback (MALL) barrier counters:  1024+(g*2+round)*32
//   [2080] abort   [2112] startup counter   [2144..2399] xcd id table
//   [2432+g*32] preflight L2 test ctr   [2944+g*32] votes (MALL)   [3456+g*32] preflight barrier (MALL)
#define CTR_WORDS 4096
#define OFF_CTR   0
#define OFF_BT    33792                   // Ball_T  bf16 [1536 n][512 k]
#define OFF_WT    1606656                 // wT      bf16 [3][512 j][512 k] (transposed + swizzled)
#define OFF_HB    3179520                 // hbuf    bf16 [256][512]
#define OFF_UB    3441664                 // ubuf    bf16 [256][512]
#define OFF_PRE   3703808                 // pre     bf16 [3][T][B][512]
#define WS_NEED   205030400ULL

static __device__ __forceinline__ unsigned short f2bf(float f) {
  union { float f; unsigned u; } v; v.f = f;
  unsigned r = v.u + 0x7FFFu + ((v.u >> 16) & 1u);   // round-to-nearest-even
  return (unsigned short)(r >> 16);
}
static __device__ __forceinline__ float bf2f(unsigned short h) {
  union { unsigned u; float f; } v; v.u = ((unsigned)h) << 16; return v.f;
}
static __device__ __forceinline__ float sigm(float x) {
  float e = exp2f(-1.4426950408889634f * x);
  return __builtin_amdgcn_rcpf(1.0f + e);
}
static __device__ __forceinline__ float tanh_f(float x) {
  float e = exp2f(2.8853900817779268f * x);          // exp(2x)
  return 1.0f - 2.0f * __builtin_amdgcn_rcpf(e + 1.0f);
}

// ---- device-scope (MALL) accessors — PROVEN correct in round 2 ----
static __device__ __forceinline__ void st_b16_dev(void* p, unsigned v) {
  asm volatile("global_store_short %0, %1, off sc0 sc1" :: "v"(p), "v"(v) : "memory");
}
static __device__ __forceinline__ void st_u32_dev(void* p, unsigned v) {
  asm volatile("global_store_dword %0, %1, off sc0 sc1" :: "v"(p), "v"(v) : "memory");
}
static __device__ __forceinline__ unsigned ld_u32_dev(const void* p) {
  unsigned v;
  asm volatile("global_load_dword %0, %1, off sc0 sc1\n\ts_waitcnt vmcnt(0)"
               : "=v"(v) : "v"(p) : "memory");
  return v;
}
// L2 return-atomic (TCC-level) — signal/poll only, never data. PROVEN functional in r4 preflight.
static __device__ __forceinline__ unsigned at_add_ret_l2(void* p, unsigned d) {
  unsigned v;
  asm volatile("global_atomic_add %0, %1, %2, off sc0\n\ts_waitcnt vmcnt(0)"
               : "=&v"(v) : "v"(p), "v"(d) : "memory");
  return v;
}
static __device__ __forceinline__ void ld4_b128_dev(const void* p0, const void* p1,
                                                    const void* p2, const void* p3,
                                                    f32x4& a, f32x4& b, f32x4& c, f32x4& d) {
  asm volatile("global_load_dwordx4 %0, %4, off sc0 sc1\n\t"
               "global_load_dwordx4 %1, %5, off sc0 sc1\n\t"
               "global_load_dwordx4 %2, %6, off sc0 sc1\n\t"
               "global_load_dwordx4 %3, %7, off sc0 sc1\n\t"
               "s_waitcnt vmcnt(0)"
               : "=&v"(a), "=&v"(b), "=&v"(c), "=&v"(d)
               : "v"(p0), "v"(p1), "v"(p2), "v"(p3)
               : "memory");
}

// ================= prep =================
__global__ void __launch_bounds__(256) k_prep(
    const float* __restrict__ wxz, const float* __restrict__ wxr, const float* __restrict__ wxh,
    const float* __restrict__ wcz, const float* __restrict__ wcr, const float* __restrict__ wch,
    const float* __restrict__ whz, const float* __restrict__ whr, const float* __restrict__ whh,
    unsigned* __restrict__ ctr, ushort_t* __restrict__ bt, ushort_t* __restrict__ wT)
{
  int e = blockIdx.x * 256 + threadIdx.x;          // grid covers 786432 exactly
  if (e < CTR_WORDS) ctr[e] = 0u;

  {
    int n = e >> 9, k = e & 511;
    int g = n >> 9, j = n & 511;
    const float* wx = (g == 0) ? wxz : (g == 1) ? wxr : wxh;
    const float* wc = (g == 0) ? wcz : (g == 1) ? wcr : wch;
    float v = (k < 256) ? wx[k * 512 + j] : wc[(k - 256) * 512 + j];
    bt[e] = f2bf(v);
  }
  {
    int g = e >> 18, rem = e & 262143;
    int j = rem >> 9, k = rem & 511;
    const float* wh = (g == 0) ? whz : (g == 1) ? whr : whh;
    wT[g * 262144 + j * 512 + (k ^ ((j & 7) << 3))] = f2bf(wh[k * 512 + j]);
  }
}

// ================= pre-GEMM =================
__global__ void __launch_bounds__(256) k_pregemm(
    const float* __restrict__ x, const float* __restrict__ c,
    const ushort_t* __restrict__ bt,
    const float* __restrict__ b_z, const float* __restrict__ b_r, const float* __restrict__ b_h,
    ushort_t* __restrict__ pre)
{
  __shared__ ushort_t As[128 * 64];
  __shared__ ushort_t Bs[128 * 64];
  int blk = blockIdx.x;
  int bm = blk % 512, bn = blk / 512;
  int tid = threadIdx.x, lane = tid & 63, wv = tid >> 6;
  int wm = (wv >> 1) * 64, wn = (wv & 1) * 64;
  int cl = lane & 15, rg = lane >> 4;
  f32x4 acc[4][4] = {};

  for (int kt = 0; kt < 8; ++kt) {
    int k0 = kt * 64;
    const float* srcA = (k0 < 256) ? x : c;
    int kbase = (k0 < 256) ? k0 : (k0 - 256);
    #pragma unroll
    for (int i = 0; i < 4; ++i) {
      int ch = tid + 256 * i;
      int m = ch >> 3, k8 = ch & 7;
      const float* p = srcA + (size_t)(bm * 128 + m) * 256 + kbase + k8 * 8;
      float4 f0 = *(const float4*)p;
      float4 f1 = *(const float4*)(p + 4);
      bf16x8 v;
      v[0]=(short)f2bf(f0.x); v[1]=(short)f2bf(f0.y); v[2]=(short)f2bf(f0.z); v[3]=(short)f2bf(f0.w);
      v[4]=(short)f2bf(f1.x); v[5]=(short)f2bf(f1.y); v[6]=(short)f2bf(f1.z); v[7]=(short)f2bf(f1.w);
      *(bf16x8*)((char*)As + ((m * 128 + k8 * 16) ^ ((m & 7) << 4))) = v;
    }
    #pragma unroll
    for (int i = 0; i < 4; ++i) {
      int ch = tid + 256 * i;
      int n = ch >> 3, k8 = ch & 7;
      int k8s = k8 ^ (n & 7);
      bf16x8 v = *(const bf16x8*)(bt + (size_t)(bn * 128 + n) * 512 + k0 + k8s * 8);
      *(bf16x8*)((char*)Bs + (n * 128 + k8 * 16)) = v;
    }
    __syncthreads();
    #pragma unroll
    for (int kk = 0; kk < 2; ++kk) {
      bf16x8 af[4], bfr[4];
      int kb = kk * 32 + rg * 8;
      #pragma unroll
      for (int fm = 0; fm < 4; ++fm) {
        int m = wm + fm * 16 + cl;
        af[fm] = *(const bf16x8*)((char*)As + (((m * 64 + kb) * 2) ^ ((m & 7) << 4)));
      }
      #pragma unroll
      for (int fn = 0; fn < 4; ++fn) {
        int n = wn + fn * 16 + cl;
        bfr[fn] = *(const bf16x8*)((char*)Bs + (((n * 64 + kb) * 2) ^ ((n & 7) << 4)));
      }
      #pragma unroll
      for (int fm = 0; fm < 4; ++fm)
        #pragma unroll
        for (int fn = 0; fn < 4; ++fn)
          acc[fm][fn] = __builtin_amdgcn_mfma_f32_16x16x32_bf16(af[fm], bfr[fn], acc[fm][fn], 0, 0, 0);
    }
    __syncthreads();
  }
  #pragma unroll
  for (int fm = 0; fm < 4; ++fm)
    #pragma unroll
    for (int fn = 0; fn < 4; ++fn) {
      int ng = bn * 128 + wn + fn * 16 + cl;
      int g = ng >> 9, j = ng & 511;
      const float* bias = (g == 0) ? b_z : (g == 1) ? b_r : b_h;
      float bv = bias[j];
      #pragma unroll
      for (int i = 0; i < 4; ++i) {
        int M = bm * 128 + wm + fm * 16 + rg * 4 + i;   // M = b*T + t
        int b = M >> 8, t = M & 255;
        pre[(((size_t)g * 256 + t) * 256 + b) * 512 + j] = f2bf(acc[fm][fn][i] + bv);
      }
    }
}

// ================= scan =================
struct ScanArgs {
  const ushort_t* wT;
  const ushort_t* pre;
  ushort_t* hbuf;
  ushort_t* ubuf;
  unsigned* ctr;
  const float* h0;
  float* hs;            // d_out + 65536, [B][T][512] f32
};
#define SMEM_SCAN 134400

// exchange read: ALWAYS device-scope MALL loads (proven), swizzle-store into LDS
static __device__ __forceinline__ void xchg_read_swz(const ushort_t* __restrict__ src,
                                                     ushort_t* dst, int tid) {
  const void* p[4];
  f32x4 v0, v1, v2, v3;
  #pragma unroll
  for (int i = 0; i < 4; ++i) { int ch = tid + 256 * i; p[i] = src + (size_t)ch * 8; }
  ld4_b128_dev(p[0], p[1], p[2], p[3], v0, v1, v2, v3);
  f32x4 vv[4] = { v0, v1, v2, v3 };
  #pragma unroll
  for (int i = 0; i < 4; ++i) {
    int ch = tid + 256 * i;
    int row = ch >> 6, k8 = ch & 63;
    *(f32x4*)((char*)dst + (((row * 512 + k8 * 8) * 2) ^ ((row & 7) << 4))) = vv[i];
  }
}

static __device__ __forceinline__ void fill_init(const float* __restrict__ src,
                                                 ushort_t* hA, float* hsl, int J, int tid) {
  #pragma unroll
  for (int i = 0; i < 4; ++i) {
    int ch = tid + 256 * i;
    int row = ch >> 6, k8 = ch & 63;
    const float* p = src + (size_t)row * 512 + k8 * 8;
    float4 f0 = *(const float4*)p;
    float4 f1 = *(const float4*)(p + 4);
    bf16x8 v;
    v[0]=(short)f2bf(f0.x); v[1]=(short)f2bf(f0.y); v[2]=(short)f2bf(f0.z); v[3]=(short)f2bf(f0.w);
    v[4]=(short)f2bf(f1.x); v[5]=(short)f2bf(f1.y); v[6]=(short)f2bf(f1.z); v[7]=(short)f2bf(f1.w);
    *(bf16x8*)((char*)hA + (((row * 512 + k8 * 8) * 2) ^ ((row & 7) << 4))) = v;
    int kb = k8 * 8;
    if (kb >= J && kb < J + 32) {
      float* q = hsl + row * 32 + (kb - J);
      q[0]=f0.x; q[1]=f0.y; q[2]=f0.z; q[3]=f0.w; q[4]=f1.x; q[5]=f1.y; q[6]=f1.z; q[7]=f1.w;
    }
  }
}

__global__ void __launch_bounds__(256, 1) k_scan(ScanArgs A) {
  extern __shared__ char smem[];
  ushort_t* Wt  = (ushort_t*)smem;               // [3][32][512] bf16 swizzled
  ushort_t* hA  = (ushort_t*)(smem + 98304);     // [16][512] bf16 swizzled
  ushort_t* uA  = (ushort_t*)(smem + 114688);    // [16][512] bf16 swizzled
  float*    hsl = (float*)(smem + 131072);       // [16][32] f32
  unsigned* xcds = (unsigned*)(smem + 133120);   // [256]
  volatile int* meta = (int*)(smem + 134208);    // group, jslice, pure

  int blk = blockIdx.x;
  int tid = threadIdx.x, lane = tid & 63, wv = tid >> 6;
  int cl = lane & 15, rg = lane >> 4;
  unsigned* abortf = A.ctr + 2080;
  unsigned* startc = A.ctr + 2112;
  unsigned* idtab  = A.ctr + 2144;
  bool dead = false;

  // ---- publish XCD id, grid barrier, deterministic group formation ----
  if (tid == 0) {
    unsigned x = __builtin_amdgcn_s_getreg(6164);   // hwreg(HW_REG_XCC_ID=20, off 0, sz 4)
    st_u32_dev(idtab + blk, x);
    asm volatile("s_waitcnt vmcnt(0)" ::: "memory");
    __hip_atomic_fetch_add(startc, 1u, __ATOMIC_RELAXED, __HIP_MEMORY_SCOPE_AGENT);
  }
  {
    unsigned it = 0;
    for (;;) {
      if (ld_u32_dev(startc) >= 256u) break;
      if ((((++it) & 1023u) == 0u) && it >= (1u << 20)) {
        if (tid == 0) st_u32_dev(abortf, 1u);
        dead = true; break;
      }
    }
  }
  xcds[tid] = ld_u32_dev(idtab + tid);
  __syncthreads();
  if (tid == 0) {
    unsigned mex = xcds[blk];
    int less = 0, eqless = 0, eqtot = 0;
    for (int b = 0; b < 256; ++b) {
      unsigned v = xcds[b];
      if (v < mex) less++;
      else if (v == mex) { eqtot++; if (b < blk) eqless++; }
    }
    int idx = less + eqless;
    int g = idx >> 4;
    int pure = (g * 16 >= less) && (g * 16 + 16 <= less + eqtot) && (eqtot <= 48);
    meta[0] = g; meta[1] = idx & 15; meta[2] = pure;
  }
  __syncthreads();
  int g = meta[0];
  int mIdx = meta[1];
  int J = mIdx * 32;
  int b0 = g * 16;
  bool pure = meta[2] != 0;
  unsigned* ctrU_P = A.ctr + (g * 2 + 0) * 32;
  unsigned* ctrH_P = A.ctr + (g * 2 + 1) * 32;
  unsigned* ctrU_F = A.ctr + 1024 + (g * 2 + 0) * 32;
  unsigned* ctrH_F = A.ctr + 1024 + (g * 2 + 1) * 32;

  // ---- preflight: counter-only dry run of the L2 barrier; unanimous vote or demote ----
  if (pure) {
    unsigned* pfc = A.ctr + 2432 + g * 32;
    unsigned* vot = A.ctr + 2944 + g * 32;
    unsigned* pfb = A.ctr + 3456 + g * 32;
    if (tid == 0) {
      unsigned cnt = at_add_ret_l2(pfc, 1u) + 1u;
      unsigned it = 0;
      while (cnt < 16u && (++it) < 16384u) cnt = at_add_ret_l2(pfc, 0u);
      if (cnt >= 16u) {
        __hip_atomic_fetch_add(vot, 1u, __ATOMIC_RELAXED, __HIP_MEMORY_SCOPE_AGENT);
        asm volatile("s_waitcnt vmcnt(0)" ::: "memory");   // vote at MALL before barrier add
      }
      __hip_atomic_fetch_add(pfb, 1u, __ATOMIC_RELAXED, __HIP_MEMORY_SCOPE_AGENT);
      it = 0;
      for (;;) {
        if (ld_u32_dev(pfb) >= 16u) break;
        if ((++it) >= (1u << 18)) { st_u32_dev(abortf, 1u); dead = true; break; }
      }
      meta[2] = (!dead && ld_u32_dev(vot) >= 16u) ? 1 : 0;
    }
    __syncthreads();
    pure = meta[2] != 0;
  }

  // ---- one-time loads ----
  #pragma unroll
  for (int gt = 0; gt < 3; ++gt) {
    const ushort_t* src = A.wT + gt * 262144 + J * 512;
    ushort_t* dst = Wt + gt * 16384;
    #pragma unroll
    for (int i = 0; i < 8; ++i) {
      int ch = tid + 256 * i;
      *(bf16x8*)(dst + ch * 8) = *(const bf16x8*)(src + ch * 8);
    }
  }
  fill_init(A.h0 + (size_t)b0 * 512, hA, hsl, J, tid);
  __syncthreads();

  // hybrid barrier: signal via L2 atomic (pure) or MALL atomic (fallback); per-wave polling.
  // Data was drained to MALL (vmcnt 0) BEFORE the signal -> count==target implies data visible.
  #define GBAR(cwP, cwF, target) do {                                            \
    __syncthreads();                                                             \
    if (!dead) {                                                                 \
      unsigned it = 0;                                                           \
      if (pure) {                                                                \
        unsigned r0 = 0;                                                         \
        if (lane == 0) r0 = at_add_ret_l2((cwP), (wv == 0) ? 1u : 0u) + ((wv == 0) ? 1u : 0u); \
        unsigned cnt = __builtin_amdgcn_readfirstlane(r0);                       \
        while (cnt < (target)) {                                                 \
          if (lane == 0) r0 = at_add_ret_l2((cwP), 0u);                          \
          cnt = __builtin_amdgcn_readfirstlane(r0);                              \
          if (((++it) & 63u) == 0u) {                                            \
            unsigned ab = 0;                                                     \
            if (lane == 0) {                                                     \
              if (it >= 65536u) { st_u32_dev(abortf, 1u); ab = 1u; }             \
              else ab = ld_u32_dev(abortf);                                      \
            }                                                                    \
            if (__builtin_amdgcn_readfirstlane(ab) != 0u) { dead = true; break; }\
          }                                                                      \
        }                                                                        \
      } else {                                                                   \
        if (tid == 0) __hip_atomic_fetch_add((cwF), 1u, __ATOMIC_RELAXED, __HIP_MEMORY_SCOPE_AGENT); \
        for (;;) {                                                               \
          unsigned cnt = ld_u32_dev(cwF);                                        \
          if (cnt >= (target)) break;                                            \
          if (((++it) & 255u) == 0u) {                                           \
            if (it >= (1u << 15)) { if (tid == 0) st_u32_dev(abortf, 1u); dead = true; break; } \
            if (ld_u32_dev(abortf) != 0u) { dead = true; break; }                \
          }                                                                      \
        }                                                                        \
      }                                                                          \
    }                                                                            \
  } while (0)

  #define LOAD_PRE(tt, pgu_, phu_) do {                                          \
    int gate1 = wv >> 1;                                                         \
    int col = J + (wv & 1) * 16 + cl;                                            \
    const ushort_t* pp  = A.pre + (((size_t)gate1 * 256 + (tt)) * 256 + b0) * 512; \
    const ushort_t* pph = A.pre + (((size_t)2 * 256 + (tt)) * 256 + b0) * 512;   \
    _Pragma("unroll")                                                            \
    for (int i = 0; i < 4; ++i) {                                                \
      int row = rg * 4 + i;                                                      \
      pgu_[i] = pp[(size_t)row * 512 + col];                                     \
      phu_[i] = (wv < 2) ? pph[(size_t)row * 512 + col] : (ushort_t)0;           \
    }                                                                            \
  } while (0)

  ushort_t pgu[4], phu[4];
  LOAD_PRE(0, pgu, phu);

  #pragma unroll 1
  for (int t = 0; t < 256; ++t) {
    unsigned tgt = (unsigned)(t + 1) << 4;
    // ---- phase 1: z (waves 0,1) / r (waves 2,3), K=512, split accumulators ----
    int gate = wv >> 1;
    int jl = (wv & 1) * 16 + cl;
    f32x4 aca = {}, acb = {};
    #pragma unroll
    for (int kk = 0; kk < 8; ++kk) {
      int kb0 = (kk * 2) * 32 + rg * 8;
      int kb1 = (kk * 2 + 1) * 32 + rg * 8;
      bf16x8 av0 = *(const bf16x8*)((char*)hA + (((cl * 512 + kb0) * 2) ^ ((cl & 7) << 4)));
      bf16x8 bv0 = *(const bf16x8*)((char*)Wt + gate * 32768 + (((jl * 512 + kb0) * 2) ^ ((jl & 7) << 4)));
      aca = __builtin_amdgcn_mfma_f32_16x16x32_bf16(av0, bv0, aca, 0, 0, 0);
      bf16x8 av1 = *(const bf16x8*)((char*)hA + (((cl * 512 + kb1) * 2) ^ ((cl & 7) << 4)));
      bf16x8 bv1 = *(const bf16x8*)((char*)Wt + gate * 32768 + (((jl * 512 + kb1) * 2) ^ ((jl & 7) << 4)));
      acb = __builtin_amdgcn_mfma_f32_16x16x32_bf16(av1, bv1, acb, 0, 0, 0);
    }
    float zv[4] = {0.f, 0.f, 0.f, 0.f};
    if (wv < 2) {
      #pragma unroll
      for (int i = 0; i < 4; ++i) zv[i] = sigm(aca[i] + acb[i] + bf2f(pgu[i]));
    } else {
      #pragma unroll
      for (int i = 0; i < 4; ++i) {
        float r = sigm(aca[i] + acb[i] + bf2f(pgu[i]));
        int row = rg * 4 + i;
        float u = r * hsl[row * 32 + jl];
        st_b16_dev(A.ubuf + (size_t)(b0 + row) * 512 + J + jl, (unsigned)f2bf(u));
      }
    }
    asm volatile("s_waitcnt vmcnt(0)" ::: "memory");   // u at MALL before signal
    GBAR(ctrU_P, ctrU_F, tgt);
    xchg_read_swz(A.ubuf + (size_t)b0 * 512, uA, tid);
    // prefetch pre(t+1): plain cached loads, latency hidden under phase 2 + ctrH barrier
    ushort_t pgu2[4], phu2[4];
    {
      int tn = (t < 255) ? (t + 1) : 255;
      LOAD_PRE(tn, pgu2, phu2);
    }
    __syncthreads();
    // ---- phase 2: h_tilde + h_new (waves 0,1) ----
    float hn[4];
    int jl2 = wv * 16 + cl;
    if (wv < 2) {
      f32x4 a2 = {}, b2 = {};
      #pragma unroll
      for (int kk = 0; kk < 8; ++kk) {
        int kb0 = (kk * 2) * 32 + rg * 8;
        int kb1 = (kk * 2 + 1) * 32 + rg * 8;
        bf16x8 av0 = *(const bf16x8*)((char*)uA + (((cl * 512 + kb0) * 2) ^ ((cl & 7) << 4)));
        bf16x8 bv0 = *(const bf16x8*)((char*)Wt + 2 * 32768 + (((jl2 * 512 + kb0) * 2) ^ ((jl2 & 7) << 4)));
        a2 = __builtin_amdgcn_mfma_f32_16x16x32_bf16(av0, bv0, a2, 0, 0, 0);
        bf16x8 av1 = *(const bf16x8*)((char*)uA + (((cl * 512 + kb1) * 2) ^ ((cl & 7) << 4)));
        bf16x8 bv1 = *(const bf16x8*)((char*)Wt + 2 * 32768 + (((jl2 * 512 + kb1) * 2) ^ ((jl2 & 7) << 4)));
        b2 = __builtin_amdgcn_mfma_f32_16x16x32_bf16(av1, bv1, b2, 0, 0, 0);
      }
      #pragma unroll
      for (int i = 0; i < 4; ++i) {
        int row = rg * 4 + i;
        float th = tanh_f(a2[i] + b2[i] + bf2f(phu[i]));
        float hv = hsl[row * 32 + jl2];
        hn[i] = hv + zv[i] * (th - hv);
        hsl[row * 32 + jl2] = hn[i];
        st_b16_dev(A.hbuf + (size_t)(b0 + row) * 512 + J + jl2, (unsigned)f2bf(hn[i]));
      }
    }
    asm volatile("s_waitcnt vmcnt(0)" ::: "memory");   // h' at MALL before signal
    GBAR(ctrH_P, ctrH_F, tgt);
    xchg_read_swz(A.hbuf + (size_t)b0 * 512, hA, tid);
    // hs output store AFTER the barrier (plain cached; drains under next step)
    if (wv < 2) {
      #pragma unroll
      for (int i = 0; i < 4; ++i) {
        int b = b0 + rg * 4 + i;
        A.hs[((size_t)b * 256 + t) * 512 + J + jl2] = hn[i];
      }
    }
    #pragma unroll
    for (int i = 0; i < 4; ++i) { pgu[i] = pgu2[i]; phu[i] = phu2[i]; }
    __syncthreads();
  }
  #undef GBAR
  #undef LOAD_PRE
}

// ================= out projection =================
__global__ void __launch_bounds__(256) k_out(const float* __restrict__ hs,
                                             const float* __restrict__ w_out,
                                             const float* __restrict__ b_out,
                                             float* __restrict__ out) {
  __shared__ float hl[512];
  int b = blockIdx.x, o = threadIdx.x;
  const float* hrow = hs + ((size_t)b * 256 + 255) * 512;
  for (int i = threadIdx.x; i < 512; i += 256) hl[i] = hrow[i];
  __syncthreads();
  float acc = b_out[o];
  #pragma unroll 8
  for (int k = 0; k < 512; ++k) acc += hl[k] * w_out[k * 256 + o];
  out[(size_t)b * 256 + o] = fmaxf(acc, 0.0f);
}

// ================= host =================
extern "C" void kernel_launch(void* const* d_in, const int* in_sizes, int n_in,
                              void* d_out, int out_size, void* d_ws, size_t ws_size,
                              hipStream_t stream) {
  const float* x    = (const float*)d_in[0];
  const float* c    = (const float*)d_in[1];
  const float* h0   = (const float*)d_in[2];
  const float* wxr  = (const float*)d_in[3];
  const float* whr  = (const float*)d_in[4];
  const float* wcr  = (const float*)d_in[5];
  const float* wxz  = (const float*)d_in[6];
  const float* whz  = (const float*)d_in[7];
  const float* wcz  = (const float*)d_in[8];
  const float* wxh  = (const float*)d_in[9];
  const float* whh  = (const float*)d_in[10];
  const float* wch  = (const float*)d_in[11];
  const float* br   = (const float*)d_in[12];
  const float* bz   = (const float*)d_in[13];
  const float* bh   = (const float*)d_in[14];
  const float* wout = (const float*)d_in[15];
  const float* bout = (const float*)d_in[16];

  char* ws = (char*)d_ws;
  unsigned*  ctr  = (unsigned*)(ws + OFF_CTR);
  ushort_t*  bt   = (ushort_t*)(ws + OFF_BT);
  ushort_t*  wT   = (ushort_t*)(ws + OFF_WT);
  ushort_t*  hbuf = (ushort_t*)(ws + OFF_HB);
  ushort_t*  ubuf = (ushort_t*)(ws + OFF_UB);
  ushort_t*  pre  = (ushort_t*)(ws + OFF_PRE);
  float* out = (float*)d_out;
  float* hs  = out + 65536;

  if (ws_size < WS_NEED)
    fprintf(stderr, "[kernel] WARNING ws_size=%zu < needed %llu\n", ws_size, WS_NEED);

  k_prep<<<3072, 256, 0, stream>>>(wxz, wxr, wxh, wcz, wcr, wch, whz, whr, whh, ctr, bt, wT);
  k_pregemm<<<6144, 256, 0, stream>>>(x, c, bt, bz, br, bh, pre);

  hipFuncSetAttribute((const void*)k_scan, hipFuncAttributeMaxDynamicSharedMemorySize, SMEM_SCAN);
  ScanArgs sa{wT, pre, hbuf, ubuf, ctr, h0, hs};
  void* args[] = { &sa };
  hipError_t e = hipLaunchCooperativeKernel(k_scan, dim3(256), dim3(256), args,
                                            (unsigned)SMEM_SCAN, stream);
  if (e != hipSuccess)
    fprintf(stderr, "[kernel] coop launch failed: %d (%s)\n", (int)e, hipGetErrorString(e));

  k_out<<<256, 256, 0, stream>>>(hs, wout, bout, out);
}

// Round 7
// 1857.790 us; speedup vs baseline: 1.3309x; 1.3309x over previous
//
#include <hip/hip_runtime.h>
#include <stdint.h>
#include <stdio.h>

typedef unsigned short ushort_t;
typedef float   f32x4  __attribute__((ext_vector_type(4)));
typedef short   bf16x8 __attribute__((ext_vector_type(8)));

#define B_    256
#define T_    256
#define IN_   256
#define HID_  512

// ---------------- workspace layout (bytes) ----------------
// ctr words: [(g*2+r)*32] monotonic barrier counters (16 groups x 2 rounds, 128B apart)
//            [1040] abort flag
#define CTR_WORDS 1056
#define OFF_CTR   0
#define OFF_BT    33792                   // Ball_T  bf16 [1536 n][512 k]
#define OFF_WT    1606656                 // wT      bf16 [3][512 j][512 k] (transposed + swizzled)
#define OFF_HB    3179520                 // hbuf    bf16 [256][512]
#define OFF_UB    3441664                 // ubuf    bf16 [256][512]
#define OFF_PRE   3703808                 // pre     bf16 [3][T][B][512]
#define WS_NEED   205030400ULL

static __device__ __forceinline__ unsigned short f2bf(float f) {
  union { float f; unsigned u; } v; v.f = f;
  unsigned r = v.u + 0x7FFFu + ((v.u >> 16) & 1u);   // round-to-nearest-even
  return (unsigned short)(r >> 16);
}
static __device__ __forceinline__ float bf2f(unsigned short h) {
  union { unsigned u; float f; } v; v.u = ((unsigned)h) << 16; return v.f;
}
static __device__ __forceinline__ float sigm(float x) {
  float e = exp2f(-1.4426950408889634f * x);
  return __builtin_amdgcn_rcpf(1.0f + e);
}
static __device__ __forceinline__ float tanh_f(float x) {
  float e = exp2f(2.8853900817779268f * x);          // exp(2x)
  return 1.0f - 2.0f * __builtin_amdgcn_rcpf(e + 1.0f);
}

// ---- device-scope (MALL) accessors — the r2-PROVEN protocol ----
static __device__ __forceinline__ void st_b16_dev(void* p, unsigned v) {
  asm volatile("global_store_short %0, %1, off sc0 sc1" :: "v"(p), "v"(v) : "memory");
}
static __device__ __forceinline__ void st_u32_dev(void* p, unsigned v) {
  asm volatile("global_store_dword %0, %1, off sc0 sc1" :: "v"(p), "v"(v) : "memory");
}
static __device__ __forceinline__ unsigned ld_u32_dev(const void* p) {
  unsigned v;
  asm volatile("global_load_dword %0, %1, off sc0 sc1\n\ts_waitcnt vmcnt(0)"
               : "=v"(v) : "v"(p) : "memory");
  return v;
}
static __device__ __forceinline__ void ld4_b128_dev(const void* p0, const void* p1,
                                                    const void* p2, const void* p3,
                                                    f32x4& a, f32x4& b, f32x4& c, f32x4& d) {
  asm volatile("global_load_dwordx4 %0, %4, off sc0 sc1\n\t"
               "global_load_dwordx4 %1, %5, off sc0 sc1\n\t"
               "global_load_dwordx4 %2, %6, off sc0 sc1\n\t"
               "global_load_dwordx4 %3, %7, off sc0 sc1\n\t"
               "s_waitcnt vmcnt(0)"
               : "=&v"(a), "=&v"(b), "=&v"(c), "=&v"(d)
               : "v"(p0), "v"(p1), "v"(p2), "v"(p3)
               : "memory");
}

// ================= prep =================
__global__ void __launch_bounds__(256) k_prep(
    const float* __restrict__ wxz, const float* __restrict__ wxr, const float* __restrict__ wxh,
    const float* __restrict__ wcz, const float* __restrict__ wcr, const float* __restrict__ wch,
    const float* __restrict__ whz, const float* __restrict__ whr, const float* __restrict__ whh,
    unsigned* __restrict__ ctr, ushort_t* __restrict__ bt, ushort_t* __restrict__ wT)
{
  int e = blockIdx.x * 256 + threadIdx.x;          // grid covers 786432 exactly
  if (e < CTR_WORDS) ctr[e] = 0u;

  {
    int n = e >> 9, k = e & 511;
    int g = n >> 9, j = n & 511;
    const float* wx = (g == 0) ? wxz : (g == 1) ? wxr : wxh;
    const float* wc = (g == 0) ? wcz : (g == 1) ? wcr : wch;
    float v = (k < 256) ? wx[k * 512 + j] : wc[(k - 256) * 512 + j];
    bt[e] = f2bf(v);
  }
  {
    int g = e >> 18, rem = e & 262143;
    int j = rem >> 9, k = rem & 511;
    const float* wh = (g == 0) ? whz : (g == 1) ? whr : whh;
    wT[g * 262144 + j * 512 + (k ^ ((j & 7) << 3))] = f2bf(wh[k * 512 + j]);
  }
}

// ================= pre-GEMM =================
__global__ void __launch_bounds__(256) k_pregemm(
    const float* __restrict__ x, const float* __restrict__ c,
    const ushort_t* __restrict__ bt,
    const float* __restrict__ b_z, const float* __restrict__ b_r, const float* __restrict__ b_h,
    ushort_t* __restrict__ pre)
{
  __shared__ ushort_t As[128 * 64];
  __shared__ ushort_t Bs[128 * 64];
  int blk = blockIdx.x;
  int bm = blk % 512, bn = blk / 512;
  int tid = threadIdx.x, lane = tid & 63, wv = tid >> 6;
  int wm = (wv >> 1) * 64, wn = (wv & 1) * 64;
  int cl = lane & 15, rg = lane >> 4;
  f32x4 acc[4][4] = {};

  for (int kt = 0; kt < 8; ++kt) {
    int k0 = kt * 64;
    const float* srcA = (k0 < 256) ? x : c;
    int kbase = (k0 < 256) ? k0 : (k0 - 256);
    #pragma unroll
    for (int i = 0; i < 4; ++i) {
      int ch = tid + 256 * i;
      int m = ch >> 3, k8 = ch & 7;
      const float* p = srcA + (size_t)(bm * 128 + m) * 256 + kbase + k8 * 8;
      float4 f0 = *(const float4*)p;
      float4 f1 = *(const float4*)(p + 4);
      bf16x8 v;
      v[0]=(short)f2bf(f0.x); v[1]=(short)f2bf(f0.y); v[2]=(short)f2bf(f0.z); v[3]=(short)f2bf(f0.w);
      v[4]=(short)f2bf(f1.x); v[5]=(short)f2bf(f1.y); v[6]=(short)f2bf(f1.z); v[7]=(short)f2bf(f1.w);
      *(bf16x8*)((char*)As + ((m * 128 + k8 * 16) ^ ((m & 7) << 4))) = v;
    }
    #pragma unroll
    for (int i = 0; i < 4; ++i) {
      int ch = tid + 256 * i;
      int n = ch >> 3, k8 = ch & 7;
      int k8s = k8 ^ (n & 7);
      bf16x8 v = *(const bf16x8*)(bt + (size_t)(bn * 128 + n) * 512 + k0 + k8s * 8);
      *(bf16x8*)((char*)Bs + (n * 128 + k8 * 16)) = v;
    }
    __syncthreads();
    #pragma unroll
    for (int kk = 0; kk < 2; ++kk) {
      bf16x8 af[4], bfr[4];
      int kb = kk * 32 + rg * 8;
      #pragma unroll
      for (int fm = 0; fm < 4; ++fm) {
        int m = wm + fm * 16 + cl;
        af[fm] = *(const bf16x8*)((char*)As + (((m * 64 + kb) * 2) ^ ((m & 7) << 4)));
      }
      #pragma unroll
      for (int fn = 0; fn < 4; ++fn) {
        int n = wn + fn * 16 + cl;
        bfr[fn] = *(const bf16x8*)((char*)Bs + (((n * 64 + kb) * 2) ^ ((n & 7) << 4)));
      }
      #pragma unroll
      for (int fm = 0; fm < 4; ++fm)
        #pragma unroll
        for (int fn = 0; fn < 4; ++fn)
          acc[fm][fn] = __builtin_amdgcn_mfma_f32_16x16x32_bf16(af[fm], bfr[fn], acc[fm][fn], 0, 0, 0);
    }
    __syncthreads();
  }
  #pragma unroll
  for (int fm = 0; fm < 4; ++fm)
    #pragma unroll
    for (int fn = 0; fn < 4; ++fn) {
      int ng = bn * 128 + wn + fn * 16 + cl;
      int g = ng >> 9, j = ng & 511;
      const float* bias = (g == 0) ? b_z : (g == 1) ? b_r : b_h;
      float bv = bias[j];
      #pragma unroll
      for (int i = 0; i < 4; ++i) {
        int M = bm * 128 + wm + fm * 16 + rg * 4 + i;   // M = b*T + t
        int b = M >> 8, t = M & 255;
        pre[(((size_t)g * 256 + t) * 256 + b) * 512 + j] = f2bf(acc[fm][fn][i] + bv);
      }
    }
}

// ================= scan =================
struct ScanArgs {
  const ushort_t* wT;
  const ushort_t* pre;
  ushort_t* hbuf;
  ushort_t* ubuf;
  unsigned* ctr;
  const float* h0;
  float* hs;            // d_out + 65536, [B][T][512] f32
};
#define SMEM_SCAN 133120

// per-wave exchange read: wave wv reads rows {wv, wv+4, wv+8, wv+12} (lane = 16B chunk in row)
static __device__ __forceinline__ void xchg_read_wave(const ushort_t* __restrict__ src,
                                                      ushort_t* dst, int wv, int lane) {
  const void* p[4];
  f32x4 v0, v1, v2, v3;
  #pragma unroll
  for (int i = 0; i < 4; ++i) {
    int row = wv + 4 * i;
    p[i] = src + (size_t)row * 512 + lane * 8;
  }
  ld4_b128_dev(p[0], p[1], p[2], p[3], v0, v1, v2, v3);
  f32x4 vv[4] = { v0, v1, v2, v3 };
  #pragma unroll
  for (int i = 0; i < 4; ++i) {
    int row = wv + 4 * i;
    *(f32x4*)((char*)dst + (((row * 512 + lane * 8) * 2) ^ ((row & 7) << 4))) = vv[i];
  }
}

static __device__ __forceinline__ void fill_init(const float* __restrict__ src,
                                                 ushort_t* hA, float* hsl, int J, int tid) {
  #pragma unroll
  for (int i = 0; i < 4; ++i) {
    int ch = tid + 256 * i;
    int row = ch >> 6, k8 = ch & 63;
    const float* p = src + (size_t)row * 512 + k8 * 8;
    float4 f0 = *(const float4*)p;
    float4 f1 = *(const float4*)(p + 4);
    bf16x8 v;
    v[0]=(short)f2bf(f0.x); v[1]=(short)f2bf(f0.y); v[2]=(short)f2bf(f0.z); v[3]=(short)f2bf(f0.w);
    v[4]=(short)f2bf(f1.x); v[5]=(short)f2bf(f1.y); v[6]=(short)f2bf(f1.z); v[7]=(short)f2bf(f1.w);
    *(bf16x8*)((char*)hA + (((row * 512 + k8 * 8) * 2) ^ ((row & 7) << 4))) = v;
    int kb = k8 * 8;
    if (kb >= J && kb < J + 32) {
      float* q = hsl + row * 32 + (kb - J);
      q[0]=f0.x; q[1]=f0.y; q[2]=f0.z; q[3]=f0.w; q[4]=f1.x; q[5]=f1.y; q[6]=f1.z; q[7]=f1.w;
    }
  }
}

__global__ void __launch_bounds__(256, 1) k_scan(ScanArgs A) {
  extern __shared__ char smem[];
  ushort_t* Wt  = (ushort_t*)smem;               // [3][32][512] bf16 swizzled
  ushort_t* hA  = (ushort_t*)(smem + 98304);     // [16][512] bf16 swizzled
  ushort_t* uA  = (ushort_t*)(smem + 114688);    // [16][512] bf16 swizzled
  float*    hsl = (float*)(smem + 131072);       // [16][32] f32

  int blk = blockIdx.x;
  int g = blk & 15, J = (blk >> 4) * 32;
  int b0 = g * 16;
  int tid = threadIdx.x, lane = tid & 63, wv = tid >> 6;
  int cl = lane & 15, rg = lane >> 4;
  unsigned* ctrU = A.ctr + (g * 2 + 0) * 32;
  unsigned* ctrH = A.ctr + (g * 2 + 1) * 32;
  unsigned* abortf = A.ctr + 1040;
  bool dead = false;

  // ---- one-time loads ----
  #pragma unroll
  for (int gt = 0; gt < 3; ++gt) {
    const ushort_t* src = A.wT + gt * 262144 + J * 512;
    ushort_t* dst = Wt + gt * 16384;
    #pragma unroll
    for (int i = 0; i < 8; ++i) {
      int ch = tid + 256 * i;
      *(bf16x8*)(dst + ch * 8) = *(const bf16x8*)(src + ch * 8);
    }
  }
  fill_init(A.h0 + (size_t)b0 * 512, hA, hsl, J, tid);
  __syncthreads();

  // per-wave poll with plain loads (read-shared line; no RMW serialization)
  #define WPOLL(cw, target) do {                                                 \
    if (!dead) {                                                                 \
      unsigned it = 0;                                                           \
      for (;;) {                                                                 \
        unsigned r0 = 0;                                                         \
        if (lane == 0) r0 = ld_u32_dev(cw);                                      \
        unsigned cnt = __builtin_amdgcn_readfirstlane(r0);                       \
        if (cnt >= (target)) break;                                              \
        if (((++it) & 255u) == 0u) {                                             \
          unsigned ab = 0;                                                       \
          if (lane == 0) {                                                       \
            if (it >= (1u << 15)) { st_u32_dev(abortf, 1u); ab = 1u; }           \
            else ab = ld_u32_dev(abortf);                                        \
          }                                                                      \
          if (__builtin_amdgcn_readfirstlane(ab) != 0u) { dead = true; break; }  \
        }                                                                        \
      }                                                                          \
    }                                                                            \
  } while (0)

  #define LOAD_PRE(tt, pgu_, phu_) do {                                          \
    int gate1 = wv >> 1;                                                         \
    int col = J + (wv & 1) * 16 + cl;                                            \
    const ushort_t* pp  = A.pre + (((size_t)gate1 * 256 + (tt)) * 256 + b0) * 512; \
    const ushort_t* pph = A.pre + (((size_t)2 * 256 + (tt)) * 256 + b0) * 512;   \
    _Pragma("unroll")                                                            \
    for (int i = 0; i < 4; ++i) {                                                \
      int row = rg * 4 + i;                                                      \
      pgu_[i] = pp[(size_t)row * 512 + col];                                     \
      phu_[i] = (wv < 2) ? pph[(size_t)row * 512 + col] : (ushort_t)0;           \
    }                                                                            \
  } while (0)

  ushort_t pgu[4], phu[4];
  LOAD_PRE(0, pgu, phu);

  #pragma unroll 1
  for (int t = 0; t < 256; ++t) {
    unsigned tgt = (unsigned)(t + 1) << 4;
    // issue next-step pre prefetch NOW; latency hides under phase-1 MFMA + barrier
    ushort_t pgu2[4], phu2[4];
    {
      int tn = (t < 255) ? (t + 1) : 255;
      LOAD_PRE(tn, pgu2, phu2);
    }
    // ---- phase 1: z (waves 0,1) / r (waves 2,3), K=512, split accumulators ----
    int gate = wv >> 1;
    int jl = (wv & 1) * 16 + cl;
    f32x4 aca = {}, acb = {};
    #pragma unroll
    for (int kk = 0; kk < 8; ++kk) {
      int kb0 = (kk * 2) * 32 + rg * 8;
      int kb1 = (kk * 2 + 1) * 32 + rg * 8;
      bf16x8 av0 = *(const bf16x8*)((char*)hA + (((cl * 512 + kb0) * 2) ^ ((cl & 7) << 4)));
      bf16x8 bv0 = *(const bf16x8*)((char*)Wt + gate * 32768 + (((jl * 512 + kb0) * 2) ^ ((jl & 7) << 4)));
      aca = __builtin_amdgcn_mfma_f32_16x16x32_bf16(av0, bv0, aca, 0, 0, 0);
      bf16x8 av1 = *(const bf16x8*)((char*)hA + (((cl * 512 + kb1) * 2) ^ ((cl & 7) << 4)));
      bf16x8 bv1 = *(const bf16x8*)((char*)Wt + gate * 32768 + (((jl * 512 + kb1) * 2) ^ ((jl & 7) << 4)));
      acb = __builtin_amdgcn_mfma_f32_16x16x32_bf16(av1, bv1, acb, 0, 0, 0);
    }
    float zv[4] = {0.f, 0.f, 0.f, 0.f};
    if (wv < 2) {
      #pragma unroll
      for (int i = 0; i < 4; ++i) zv[i] = sigm(aca[i] + acb[i] + bf2f(pgu[i]));
    } else {
      #pragma unroll
      for (int i = 0; i < 4; ++i) {
        float r = sigm(aca[i] + acb[i] + bf2f(pgu[i]));
        int row = rg * 4 + i;
        float u = r * hsl[row * 32 + jl];
        st_b16_dev(A.ubuf + (size_t)(b0 + row) * 512 + J + jl, (unsigned)f2bf(u));
      }
    }
    asm volatile("s_waitcnt vmcnt(0)" ::: "memory");   // u at MALL before signal
    __syncthreads();
    if (tid == 0) __hip_atomic_fetch_add(ctrU, 1u, __ATOMIC_RELAXED, __HIP_MEMORY_SCOPE_AGENT);
    WPOLL(ctrU, tgt);
    xchg_read_wave(A.ubuf + (size_t)b0 * 512, uA, wv, lane);   // per-wave, immediate
    __syncthreads();
    // ---- phase 2: h_tilde + h_new (waves 0,1) ----
    float hn[4];
    int jl2 = wv * 16 + cl;
    if (wv < 2) {
      f32x4 a2 = {}, b2 = {};
      #pragma unroll
      for (int kk = 0; kk < 8; ++kk) {
        int kb0 = (kk * 2) * 32 + rg * 8;
        int kb1 = (kk * 2 + 1) * 32 + rg * 8;
        bf16x8 av0 = *(const bf16x8*)((char*)uA + (((cl * 512 + kb0) * 2) ^ ((cl & 7) << 4)));
        bf16x8 bv0 = *(const bf16x8*)((char*)Wt + 2 * 32768 + (((jl2 * 512 + kb0) * 2) ^ ((jl2 & 7) << 4)));
        a2 = __builtin_amdgcn_mfma_f32_16x16x32_bf16(av0, bv0, a2, 0, 0, 0);
        bf16x8 av1 = *(const bf16x8*)((char*)uA + (((cl * 512 + kb1) * 2) ^ ((cl & 7) << 4)));
        bf16x8 bv1 = *(const bf16x8*)((char*)Wt + 2 * 32768 + (((jl2 * 512 + kb1) * 2) ^ ((jl2 & 7) << 4)));
        b2 = __builtin_amdgcn_mfma_f32_16x16x32_bf16(av1, bv1, b2, 0, 0, 0);
      }
      #pragma unroll
      for (int i = 0; i < 4; ++i) {
        int row = rg * 4 + i;
        float th = tanh_f(a2[i] + b2[i] + bf2f(phu[i]));
        float hv = hsl[row * 32 + jl2];
        hn[i] = hv + zv[i] * (th - hv);
        hsl[row * 32 + jl2] = hn[i];
        st_b16_dev(A.hbuf + (size_t)(b0 + row) * 512 + J + jl2, (unsigned)f2bf(hn[i]));
      }
    }
    asm volatile("s_waitcnt vmcnt(0)" ::: "memory");   // h' at MALL before signal
    __syncthreads();
    if (tid == 0) __hip_atomic_fetch_add(ctrH, 1u, __ATOMIC_RELAXED, __HIP_MEMORY_SCOPE_AGENT);
    WPOLL(ctrH, tgt);
    xchg_read_wave(A.hbuf + (size_t)b0 * 512, hA, wv, lane);   // per-wave, immediate
    // hs output store AFTER the barrier (plain cached; drains under next step)
    if (wv < 2) {
      #pragma unroll
      for (int i = 0; i < 4; ++i) {
        int b = b0 + rg * 4 + i;
        A.hs[((size_t)b * 256 + t) * 512 + J + jl2] = hn[i];
      }
    }
    #pragma unroll
    for (int i = 0; i < 4; ++i) { pgu[i] = pgu2[i]; phu[i] = phu2[i]; }
    __syncthreads();
  }
  #undef WPOLL
  #undef LOAD_PRE
}

// ================= out projection =================
__global__ void __launch_bounds__(256) k_out(const float* __restrict__ hs,
                                             const float* __restrict__ w_out,
                                             const float* __restrict__ b_out,
                                             float* __restrict__ out) {
  __shared__ float hl[512];
  int b = blockIdx.x, o = threadIdx.x;
  const float* hrow = hs + ((size_t)b * 256 + 255) * 512;
  for (int i = threadIdx.x; i < 512; i += 256) hl[i] = hrow[i];
  __syncthreads();
  float acc = b_out[o];
  #pragma unroll 8
  for (int k = 0; k < 512; ++k) acc += hl[k] * w_out[k * 256 + o];
  out[(size_t)b * 256 + o] = fmaxf(acc, 0.0f);
}

// ================= host =================
extern "C" void kernel_launch(void* const* d_in, const int* in_sizes, int n_in,
                              void* d_out, int out_size, void* d_ws, size_t ws_size,
                              hipStream_t stream) {
  const float* x    = (const float*)d_in[0];
  const float* c    = (const float*)d_in[1];
  const float* h0   = (const float*)d_in[2];
  const float* wxr  = (const float*)d_in[3];
  const float* whr  = (const float*)d_in[4];
  const float* wcr  = (const float*)d_in[5];
  const float* wxz  = (const float*)d_in[6];
  const float* whz  = (const float*)d_in[7];
  const float* wcz  = (const float*)d_in[8];
  const float* wxh  = (const float*)d_in[9];
  const float* whh  = (const float*)d_in[10];
  const float* wch  = (const float*)d_in[11];
  const float* br   = (const float*)d_in[12];
  const float* bz   = (const float*)d_in[13];
  const float* bh   = (const float*)d_in[14];
  const float* wout = (const float*)d_in[15];
  const float* bout = (const float*)d_in[16];

  char* ws = (char*)d_ws;
  unsigned*  ctr  = (unsigned*)(ws + OFF_CTR);
  ushort_t*  bt   = (ushort_t*)(ws + OFF_BT);
  ushort_t*  wT   = (ushort_t*)(ws + OFF_WT);
  ushort_t*  hbuf = (ushort_t*)(ws + OFF_HB);
  ushort_t*  ubuf = (ushort_t*)(ws + OFF_UB);
  ushort_t*  pre  = (ushort_t*)(ws + OFF_PRE);
  float* out = (float*)d_out;
  float* hs  = out + 65536;

  if (ws_size < WS_NEED)
    fprintf(stderr, "[kernel] WARNING ws_size=%zu < needed %llu\n", ws_size, WS_NEED);

  k_prep<<<3072, 256, 0, stream>>>(wxz, wxr, wxh, wcz, wcr, wch, whz, whr, whh, ctr, bt, wT);
  k_pregemm<<<6144, 256, 0, stream>>>(x, c, bt, bz, br, bh, pre);

  hipFuncSetAttribute((const void*)k_scan, hipFuncAttributeMaxDynamicSharedMemorySize, SMEM_SCAN);
  ScanArgs sa{wT, pre, hbuf, ubuf, ctr, h0, hs};
  void* args[] = { &sa };
  hipError_t e = hipLaunchCooperativeKernel(k_scan, dim3(256), dim3(256), args,
                                            (unsigned)SMEM_SCAN, stream);
  if (e != hipSuccess)
    fprintf(stderr, "[kernel] coop launch failed: %d (%s)\n", (int)e, hipGetErrorString(e));

  k_out<<<256, 256, 0, stream>>>(hs, wout, bout, out);
}